// Round 7
// baseline (225.607 us; speedup 1.0000x reference)
//
#include <hip/hip_runtime.h>
#include <hip/hip_bf16.h>
#include <math.h>

#define D 256
#define S 4096
#define BATCH 4
#define RPB 32         // rows per block in fused kernel (R4 config)
#define DT_CUT 7.0f
#define REP 8          // DIAGNOSTIC: idempotent repeat so kernels surface in rocprof top-5

typedef __attribute__((ext_vector_type(8))) short short8;
typedef __attribute__((ext_vector_type(4))) float f32x4;

static __device__ __forceinline__ unsigned short f2bf(float x) {
    union { __hip_bfloat16 b; unsigned short u; } cv;
    cv.b = __float2bfloat16(x);    // HW RNE convert
    return cv.u;
}

// ---------------------------------------------------------------------------
// K1: transposed bf16 embedding embT[b][d][j] (+ W->bf16 in blocks 0..255).
// ---------------------------------------------------------------------------
__global__ __launch_bounds__(256) void embt_kernel(const float* __restrict__ t,
                                                   const float* __restrict__ W,
                                                   unsigned short* __restrict__ embT,
                                                   unsigned short* __restrict__ Wb) {
    int blk = blockIdx.x;
    int tid = threadIdx.x;
    for (int rep = 0; rep < REP; ++rep) {
        if (blk < 256) Wb[blk * 256 + tid] = f2bf(W[blk * 256 + tid]);
        int b   = blk >> 7;
        int kg  = (blk >> 4) & 7;
        int jc  = blk & 15;
        int j   = jc * 256 + tid;
        float tv = t[b * S + j];
        const float c2 = -0.1038102552f;           // -2*log2(10000)/256
#pragma unroll
        for (int kk = 0; kk < 16; ++kk) {
            int k = kg * 16 + kk;
            float te = tv * exp2f(c2 * (float)(k + 1));
            float sn, cs;
            __sincosf(te, &sn, &cs);
            embT[((size_t)(b * D + 2 * k)) * S + j]     = f2bf(sn);
            embT[((size_t)(b * D + 2 * k + 1)) * S + j] = f2bf(cs);
        }
    }
}

// ---------------------------------------------------------------------------
// K2: fused band-GEMM (MFMA) + LayerNorm + decoder-GEMM (MFMA) + softplus.
// Exact R4 structure (RPB=32, 2 Mt tiles; unpipelined band, pipelined decoder),
// wrapped in an idempotent REP loop for counter visibility.
// ---------------------------------------------------------------------------
__global__ __launch_bounds__(256) void fused_kernel(
    const float* __restrict__ t, const unsigned short* __restrict__ embT,
    const unsigned short* __restrict__ Wb,
    const float* __restrict__ gamma, const float* __restrict__ beta,
    const float* __restrict__ w_t, const float* __restrict__ b_t,
    float* __restrict__ out) {
    int blk  = blockIdx.x;
    int b    = blk >> 7;                 // 128 blocks per batch
    int i0   = (blk & 127) * RPB;
    int tid  = threadIdx.x;
    int w    = tid >> 6;
    int lane = tid & 63;
    int ln15 = lane & 15;
    int kg   = lane >> 4;
    const float* tb = t + b * S;

    __shared__ float2 s_ln[4][RPB];
    __shared__ unsigned short H[RPB][264];       // +8 pad: conflict-free b128
    __shared__ float s_dec[4][RPB];

    for (int rep = 0; rep < REP; ++rep) {
    __syncthreads();

    float ti[2];
    ti[0] = tb[i0 + ln15];
    ti[1] = tb[i0 + 16 + ln15];

    // ---- 64-ary cooperative lower_bound: first j with t[j] >= t[i0]-DT_CUT
    float tcut = tb[i0] - DT_CUT;
    int lo = 0, hi = i0;                 // invariant: t[hi] >= tcut
    while (hi > lo) {
        int step = ((hi - lo) + 63) >> 6;
        int p = min(lo + lane * step, hi);
        unsigned long long mb = __ballot(tb[p] < tcut);
        int cnt = __popcll(mb);
        int nlo = (cnt == 0) ? lo : (lo + (cnt - 1) * step + 1);
        int nhi = (cnt == 0) ? nlo : min(lo + cnt * step, hi);
        lo = nlo; hi = nhi;
    }
    int jmin = lo & ~31;                 // align chunks; extra j's have score~0
    int jmax = i0 + RPB - 1;

    // ---- band GEMM: C[m, d] += scores[m, k] * embT[d, k]
    f32x4 acc[2][4];
#pragma unroll
    for (int Mt = 0; Mt < 2; ++Mt)
#pragma unroll
        for (int nt = 0; nt < 4; ++nt) acc[Mt][nt] = (f32x4){0.f, 0.f, 0.f, 0.f};

    for (int j0 = jmin; j0 <= jmax; j0 += 32) {
        int jb = min(j0 + kg * 8, S - 8);          // clamp tail (masked lanes only)
        float4 tja = *(const float4*)&tb[jb];
        float4 tjb = *(const float4*)&tb[jb + 4];
        float tj[8] = {tja.x, tja.y, tja.z, tja.w, tjb.x, tjb.y, tjb.z, tjb.w};
        short8 af[2];
#pragma unroll
        for (int Mt = 0; Mt < 2; ++Mt) {
            union { short8 v; unsigned short u[8]; } a;
            float tiv = ti[Mt];
            int irow = i0 + Mt * 16 + ln15;
            if (j0 + 31 <= i0 + Mt * 16) {        // uniform: fully causal chunk
#pragma unroll
                for (int e = 0; e < 8; ++e) {
                    float dt = tiv - tj[e];
                    a.u[e] = f2bf(__expf(-0.5f * dt * dt));
                }
            } else {                               // diagonal chunk: mask j>i
#pragma unroll
                for (int e = 0; e < 8; ++e) {
                    float dt = tiv - tj[e];
                    float sc = __expf(-0.5f * dt * dt);
                    a.u[e] = (j0 + kg * 8 + e <= irow) ? f2bf(sc) : (unsigned short)0;
                }
            }
            af[Mt] = a.v;
        }
        const unsigned short* ebase =
            embT + ((size_t)(b * D) + w * 64 + ln15) * S + j0 + kg * 8;
#pragma unroll
        for (int nt = 0; nt < 4; ++nt) {
            short8 bf = *(const short8*)(ebase + (size_t)nt * 16 * S);
            acc[0][nt] = __builtin_amdgcn_mfma_f32_16x16x32_bf16(af[0], bf, acc[0][nt], 0, 0, 0);
            acc[1][nt] = __builtin_amdgcn_mfma_f32_16x16x32_bf16(af[1], bf, acc[1][nt], 0, 0, 0);
        }
    }

    // ---- LayerNorm (rows = Mt*16 + kg*4 + reg per lane)
#pragma unroll
    for (int Mt = 0; Mt < 2; ++Mt)
#pragma unroll
        for (int reg = 0; reg < 4; ++reg) {
            float s = acc[Mt][0][reg] + acc[Mt][1][reg] + acc[Mt][2][reg] + acc[Mt][3][reg];
            float q = acc[Mt][0][reg] * acc[Mt][0][reg] + acc[Mt][1][reg] * acc[Mt][1][reg]
                    + acc[Mt][2][reg] * acc[Mt][2][reg] + acc[Mt][3][reg] * acc[Mt][3][reg];
#pragma unroll
            for (int m = 1; m < 16; m <<= 1) {
                s += __shfl_xor(s, m);
                q += __shfl_xor(q, m);
            }
            if (ln15 == 0) s_ln[w][Mt * 16 + kg * 4 + reg] = make_float2(s, q);
        }
    __syncthreads();

    float g[4], be[4];
#pragma unroll
    for (int nt = 0; nt < 4; ++nt) {
        g[nt]  = gamma[w * 64 + nt * 16 + ln15];
        be[nt] = beta[w * 64 + nt * 16 + ln15];
    }
#pragma unroll
    for (int Mt = 0; Mt < 2; ++Mt)
#pragma unroll
        for (int reg = 0; reg < 4; ++reg) {
            int r = Mt * 16 + kg * 4 + reg;
            float2 p0 = s_ln[0][r], p1 = s_ln[1][r], p2 = s_ln[2][r], p3 = s_ln[3][r];
            float sum = p0.x + p1.x + p2.x + p3.x;
            float sq  = p0.y + p1.y + p2.y + p3.y;
            float mu  = sum * (1.0f / D);
            float var = fmaxf(sq * (1.0f / D) - mu * mu, 0.0f);
            float rstd = rsqrtf(var + 1e-6f);
#pragma unroll
            for (int nt = 0; nt < 4; ++nt) {
                float h = (acc[Mt][nt][reg] - mu) * rstd * g[nt] + be[nt];
                H[r][w * 64 + nt * 16 + ln15] = f2bf(h);
            }
        }
    __syncthreads();

    // ---- decoder GEMM: C2[m, e] = sum_d H[m, d] * Wb[e, d], pipelined kt
    f32x4 acc2[2][4];
#pragma unroll
    for (int Mt = 0; Mt < 2; ++Mt)
#pragma unroll
        for (int et = 0; et < 4; ++et) acc2[Mt][et] = (f32x4){0.f, 0.f, 0.f, 0.f};

#pragma unroll
    for (int kt = 0; kt < 8; ++kt) {
        short8 a0 = *(const short8*)&H[ln15][kt * 32 + kg * 8];
        short8 a1 = *(const short8*)&H[16 + ln15][kt * 32 + kg * 8];
        const unsigned short* wbase = Wb + (size_t)(w * 64 + ln15) * D + kt * 32 + kg * 8;
#pragma unroll
        for (int et = 0; et < 4; ++et) {
            short8 bf = *(const short8*)(wbase + (size_t)et * 16 * D);
            acc2[0][et] = __builtin_amdgcn_mfma_f32_16x16x32_bf16(a0, bf, acc2[0][et], 0, 0, 0);
            acc2[1][et] = __builtin_amdgcn_mfma_f32_16x16x32_bf16(a1, bf, acc2[1][et], 0, 0, 0);
        }
    }

    // ---- epilogue: relu -> *w_t -> reduce over e -> softplus
    float wt[4];
#pragma unroll
    for (int et = 0; et < 4; ++et) wt[et] = w_t[w * 64 + et * 16 + ln15];
#pragma unroll
    for (int Mt = 0; Mt < 2; ++Mt)
#pragma unroll
        for (int reg = 0; reg < 4; ++reg) {
            float v = 0.f;
#pragma unroll
            for (int et = 0; et < 4; ++et)
                v = fmaf(fmaxf(acc2[Mt][et][reg], 0.f), wt[et], v);
#pragma unroll
            for (int m = 1; m < 16; m <<= 1) v += __shfl_xor(v, m);
            if (ln15 == 0) s_dec[w][Mt * 16 + kg * 4 + reg] = v;
        }
    __syncthreads();
    if (tid < RPB) {
        float tot = s_dec[0][tid] + s_dec[1][tid] + s_dec[2][tid] + s_dec[3][tid] + b_t[0];
        float o = fmaxf(tot, 0.0f) + log1pf(expf(-fabsf(tot)));   // softplus
        out[(size_t)blk * RPB + tid] = o;
    }
    }   // rep
}

// ---------------------------------------------------------------------------
extern "C" void kernel_launch(void* const* d_in, const int* in_sizes, int n_in,
                              void* d_out, int out_size, void* d_ws, size_t ws_size,
                              hipStream_t stream) {
    // inputs: 0 event_type(i32) 1 event_time(f32) 2 arrival_times(f32)
    //         3 W_in 4 w_t 5 b_t 6 ln_gamma 7 ln_beta
    const float* t   = (const float*)d_in[1];
    const float* W   = (const float*)d_in[3];
    const float* wt  = (const float*)d_in[4];
    const float* bt  = (const float*)d_in[5];
    const float* gam = (const float*)d_in[6];
    const float* bet = (const float*)d_in[7];
    float* out = (float*)d_out;

    char* ws = (char*)d_ws;
    unsigned short* embT = (unsigned short*)ws;                       // 8 MiB
    unsigned short* Wb   = (unsigned short*)(ws + (size_t)8388608);   // 128 KiB

    embt_kernel<<<dim3(512), dim3(256), 0, stream>>>(t, W, embT, Wb);
    fused_kernel<<<dim3(BATCH * S / RPB), dim3(256), 0, stream>>>(
        t, embT, Wb, gam, bet, wt, bt, out);
}

// Round 8
// 34.692 us; speedup vs baseline: 6.5031x; 6.5031x over previous
//
#include <hip/hip_runtime.h>
#include <hip/hip_bf16.h>
#include <math.h>

#define D 256
#define S 4096
#define BATCH 4
#define RPB 16         // rows per block in fused kernel
#define DT_CUT 7.0f

typedef __attribute__((ext_vector_type(8))) short short8;
typedef __attribute__((ext_vector_type(4))) float f32x4;

static __device__ __forceinline__ unsigned short f2bf(float x) {
    union { __hip_bfloat16 b; unsigned short u; } cv;
    cv.b = __float2bfloat16(x);    // HW RNE convert
    return cv.u;
}

// ===========================================================================
// Fragment-tiled operand layouts (so every MFMA B-fragment load is one
// fully-coalesced contiguous 1KB wave transaction instead of a 64-line gather):
//   emb5: tile index ((b*128 + jc)*16 + (w*4 + nt)), elem = lane*8 + e
//         maps (b, j = jc*32 + (lane>>4)*8 + e, d = w*64 + nt*16 + (lane&15))
//   w5:   tile index ((w*4 + et)*8 + kt), elem = lane*8 + ee
//         maps (e = w*64 + et*16 + (lane&15), d = kt*32 + (lane>>4)*8 + ee)
// ===========================================================================

// ---------------------------------------------------------------------------
// K1: embedding in emb5 layout (LDS-staged: scatter to LDS, stream out
// coalesced). Block = (b, jc): 32 j x 256 d. Also converts W -> w5 (blk<256).
// ---------------------------------------------------------------------------
__global__ __launch_bounds__(256) void embt_kernel(const float* __restrict__ t,
                                                   const float* __restrict__ W,
                                                   unsigned short* __restrict__ emb5,
                                                   unsigned short* __restrict__ w5) {
    int blk = blockIdx.x;
    int tid = threadIdx.x;

    if (blk < 256) {               // W[e][d] -> w5 fragment tiles (scattered 2B)
        int e = blk, dd = tid;
        int wv = e >> 6, et = (e >> 4) & 3, l15 = e & 15;
        int kt = dd >> 5, kgg = (dd >> 3) & 3, ee = dd & 7;
        w5[(size_t)(((wv * 4 + et) * 8 + kt) * 512) + (kgg * 16 + l15) * 8 + ee]
            = f2bf(W[e * D + dd]);
    }

    __shared__ unsigned short tile[8192];       // 16 KiB, final global order
    int j_local = tid & 31;
    int fg      = tid >> 5;                     // 8 groups x 16 freqs
    int b       = blk >> 7;
    int jc      = blk & 127;
    float tv = t[b * S + jc * 32 + j_local];
    int kg = j_local >> 3, e = j_local & 7;
    const float c2 = -0.1038102552f;            // -2*log2(10000)/256
#pragma unroll
    for (int kk = 0; kk < 16; ++kk) {
        int k = fg * 16 + kk;
        float te = tv * exp2f(c2 * (float)(k + 1));
        float sn, cs;
        __sincosf(te, &sn, &cs);
        int base = (k >> 3) * 512 + kg * 128 + e;      // (d>>4)*512 + (kg*16+ln)*8 + e
        int ln0 = 2 * (k & 7);
        tile[base + ln0 * 8]       = f2bf(sn);         // d even -> sin
        tile[base + (ln0 + 1) * 8] = f2bf(cs);         // d odd  -> cos
    }
    __syncthreads();
    const uint4* src = (const uint4*)tile;             // 1024 x 16B
    uint4* dst = (uint4*)(emb5 + (size_t)blk * 8192);
#pragma unroll
    for (int p = 0; p < 4; ++p) dst[p * 256 + tid] = src[p * 256 + tid];
}

// ---------------------------------------------------------------------------
// K2: fused band-GEMM (MFMA) + LayerNorm + decoder-GEMM (MFMA) + softplus.
// Block = 16 rows x 256 d/e, 4 waves (wave w = d/e slice of 64).
// All global MFMA operands in fragment-tiled layout (coalesced 16B/lane).
// ---------------------------------------------------------------------------
__global__ __launch_bounds__(256, 4) void fused_kernel(
    const float* __restrict__ t, const unsigned short* __restrict__ emb5,
    const unsigned short* __restrict__ w5,
    const float* __restrict__ gamma, const float* __restrict__ beta,
    const float* __restrict__ w_t, const float* __restrict__ b_t,
    float* __restrict__ out) {
    int blk  = blockIdx.x;
    int b    = blk >> 8;                 // 256 blocks per batch
    int i0   = (blk & 255) * RPB;
    int tid  = threadIdx.x;
    int w    = tid >> 6;
    int lane = tid & 63;
    int ln15 = lane & 15;
    int kg   = lane >> 4;
    const float* tb = t + b * S;

    float ti = tb[i0 + ln15];            // A row = ln15
    int irow = i0 + ln15;

    // ---- 64-ary cooperative lower_bound: first j with t[j] >= t[i0]-DT_CUT
    float tcut = tb[i0] - DT_CUT;
    int lo = 0, hi = i0;                 // invariant: t[hi] >= tcut
    while (hi > lo) {
        int step = ((hi - lo) + 63) >> 6;
        int p = min(lo + lane * step, hi);
        unsigned long long mb = __ballot(tb[p] < tcut);
        int cnt = __popcll(mb);
        int nlo = (cnt == 0) ? lo : (lo + (cnt - 1) * step + 1);
        int nhi = (cnt == 0) ? nlo : min(lo + cnt * step, hi);
        lo = nlo; hi = nhi;
    }
    int jcmin = lo >> 5;                 // 32-aligned chunks; extras score ~0
    int jcmax = (i0 + RPB - 1) >> 5;

    // ---- band GEMM: C[m, d] += scores[m, k] * emb[k, d]
    f32x4 acc[4];
#pragma unroll
    for (int nt = 0; nt < 4; ++nt) acc[nt] = (f32x4){0.f, 0.f, 0.f, 0.f};

    const unsigned short* ebase = emb5 + ((size_t)(b * 128) * 16 + w * 4) * 512 + lane * 8;
    for (int jc = jcmin; jc <= jcmax; ++jc) {
        int j0 = jc * 32;
        // B fragments: 4 contiguous coalesced 1KB wave loads
        const unsigned short* p = ebase + (size_t)jc * 8192;
        short8 bf0 = *(const short8*)(p);
        short8 bf1 = *(const short8*)(p + 512);
        short8 bf2 = *(const short8*)(p + 1024);
        short8 bf3 = *(const short8*)(p + 1536);
        // scores (A fragment) while loads are in flight
        float4 tja = *(const float4*)&tb[j0 + kg * 8];
        float4 tjb = *(const float4*)&tb[j0 + kg * 8 + 4];
        float tj[8] = {tja.x, tja.y, tja.z, tja.w, tjb.x, tjb.y, tjb.z, tjb.w};
        union { short8 v; unsigned short u[8]; } a;
        if (j0 + 31 <= i0) {              // fully causal chunk
#pragma unroll
            for (int e = 0; e < 8; ++e) {
                float dt = ti - tj[e];
                a.u[e] = f2bf(__expf(-0.5f * dt * dt));
            }
        } else {                          // diagonal chunk: mask j > i
#pragma unroll
            for (int e = 0; e < 8; ++e) {
                float dt = ti - tj[e];
                float sc = __expf(-0.5f * dt * dt);
                a.u[e] = (j0 + kg * 8 + e <= irow) ? f2bf(sc) : (unsigned short)0;
            }
        }
        acc[0] = __builtin_amdgcn_mfma_f32_16x16x32_bf16(a.v, bf0, acc[0], 0, 0, 0);
        acc[1] = __builtin_amdgcn_mfma_f32_16x16x32_bf16(a.v, bf1, acc[1], 0, 0, 0);
        acc[2] = __builtin_amdgcn_mfma_f32_16x16x32_bf16(a.v, bf2, acc[2], 0, 0, 0);
        acc[3] = __builtin_amdgcn_mfma_f32_16x16x32_bf16(a.v, bf3, acc[3], 0, 0, 0);
    }

    // ---- LayerNorm (row m = kg*4 + reg; col d = w*64 + nt*16 + ln15)
    __shared__ float2 s_ln[4][RPB];
    __shared__ unsigned short H[RPB][264];       // +8 pad: conflict-free b128
    __shared__ float s_dec[4][RPB];

#pragma unroll
    for (int reg = 0; reg < 4; ++reg) {
        float s = acc[0][reg] + acc[1][reg] + acc[2][reg] + acc[3][reg];
        float q = acc[0][reg] * acc[0][reg] + acc[1][reg] * acc[1][reg]
                + acc[2][reg] * acc[2][reg] + acc[3][reg] * acc[3][reg];
#pragma unroll
        for (int m = 1; m < 16; m <<= 1) {
            s += __shfl_xor(s, m);
            q += __shfl_xor(q, m);
        }
        if (ln15 == 0) s_ln[w][kg * 4 + reg] = make_float2(s, q);
    }
    __syncthreads();

    float g[4], be[4];
#pragma unroll
    for (int nt = 0; nt < 4; ++nt) {
        g[nt]  = gamma[w * 64 + nt * 16 + ln15];
        be[nt] = beta[w * 64 + nt * 16 + ln15];
    }
#pragma unroll
    for (int reg = 0; reg < 4; ++reg) {
        int r = kg * 4 + reg;
        float2 p0 = s_ln[0][r], p1 = s_ln[1][r], p2 = s_ln[2][r], p3 = s_ln[3][r];
        float sum = p0.x + p1.x + p2.x + p3.x;
        float sq  = p0.y + p1.y + p2.y + p3.y;
        float mu  = sum * (1.0f / D);
        float var = fmaxf(sq * (1.0f / D) - mu * mu, 0.0f);
        float rstd = rsqrtf(var + 1e-6f);
#pragma unroll
        for (int nt = 0; nt < 4; ++nt) {
            float h = (acc[nt][reg] - mu) * rstd * g[nt] + be[nt];
            H[r][w * 64 + nt * 16 + ln15] = f2bf(h);
        }
    }
    __syncthreads();

    // ---- decoder GEMM: C2[m, e] = sum_d H[m, d] * W[e, d]
    f32x4 acc2[4];
#pragma unroll
    for (int et = 0; et < 4; ++et) acc2[et] = (f32x4){0.f, 0.f, 0.f, 0.f};

    short8 afr[8];
#pragma unroll
    for (int kt = 0; kt < 8; ++kt)
        afr[kt] = *(const short8*)&H[ln15][kt * 32 + kg * 8];

    const unsigned short* wbase = w5 + (size_t)(w * 4 * 8) * 512 + lane * 8;
#pragma unroll
    for (int kt = 0; kt < 8; ++kt) {
        short8 wf0 = *(const short8*)(wbase + (size_t)(0 * 8 + kt) * 512);
        short8 wf1 = *(const short8*)(wbase + (size_t)(1 * 8 + kt) * 512);
        short8 wf2 = *(const short8*)(wbase + (size_t)(2 * 8 + kt) * 512);
        short8 wf3 = *(const short8*)(wbase + (size_t)(3 * 8 + kt) * 512);
        acc2[0] = __builtin_amdgcn_mfma_f32_16x16x32_bf16(afr[kt], wf0, acc2[0], 0, 0, 0);
        acc2[1] = __builtin_amdgcn_mfma_f32_16x16x32_bf16(afr[kt], wf1, acc2[1], 0, 0, 0);
        acc2[2] = __builtin_amdgcn_mfma_f32_16x16x32_bf16(afr[kt], wf2, acc2[2], 0, 0, 0);
        acc2[3] = __builtin_amdgcn_mfma_f32_16x16x32_bf16(afr[kt], wf3, acc2[3], 0, 0, 0);
    }

    // ---- epilogue: relu -> *w_t -> reduce over e -> softplus
    float wt[4];
#pragma unroll
    for (int et = 0; et < 4; ++et) wt[et] = w_t[w * 64 + et * 16 + ln15];
#pragma unroll
    for (int reg = 0; reg < 4; ++reg) {
        float v = 0.f;
#pragma unroll
        for (int et = 0; et < 4; ++et)
            v = fmaf(fmaxf(acc2[et][reg], 0.f), wt[et], v);
#pragma unroll
        for (int m = 1; m < 16; m <<= 1) v += __shfl_xor(v, m);
        if (ln15 == 0) s_dec[w][kg * 4 + reg] = v;
    }
    __syncthreads();
    if (tid < RPB) {
        float tot = s_dec[0][tid] + s_dec[1][tid] + s_dec[2][tid] + s_dec[3][tid] + b_t[0];
        float o = fmaxf(tot, 0.0f) + log1pf(expf(-fabsf(tot)));   // softplus
        out[(size_t)blk * RPB + tid] = o;
    }
}

// ---------------------------------------------------------------------------
extern "C" void kernel_launch(void* const* d_in, const int* in_sizes, int n_in,
                              void* d_out, int out_size, void* d_ws, size_t ws_size,
                              hipStream_t stream) {
    // inputs: 0 event_type(i32) 1 event_time(f32) 2 arrival_times(f32)
    //         3 W_in 4 w_t 5 b_t 6 ln_gamma 7 ln_beta
    const float* t   = (const float*)d_in[1];
    const float* W   = (const float*)d_in[3];
    const float* wt  = (const float*)d_in[4];
    const float* bt  = (const float*)d_in[5];
    const float* gam = (const float*)d_in[6];
    const float* bet = (const float*)d_in[7];
    float* out = (float*)d_out;

    char* ws = (char*)d_ws;
    unsigned short* emb5 = (unsigned short*)ws;                       // 8 MiB
    unsigned short* w5   = (unsigned short*)(ws + (size_t)8388608);   // 128 KiB

    embt_kernel<<<dim3(512), dim3(256), 0, stream>>>(t, W, emb5, w5);
    fused_kernel<<<dim3(BATCH * S / RPB), dim3(256), 0, stream>>>(
        t, emb5, w5, gam, bet, wt, bt, out);
}

// Round 9
// 25.593 us; speedup vs baseline: 8.8151x; 1.3555x over previous
//
#include <hip/hip_runtime.h>
#include <hip/hip_bf16.h>
#include <math.h>

#define D 256
#define S 4096
#define BATCH 4
#define RPB 16         // rows per block in fused kernel
#define NBLK (BATCH * S / RPB)   // 1024 fused blocks
#define DT_CUT 7.0f

typedef __attribute__((ext_vector_type(8))) short short8;
typedef __attribute__((ext_vector_type(4))) float f32x4;

static __device__ __forceinline__ unsigned short f2bf(float x) {
    union { __hip_bfloat16 b; unsigned short u; } cv;
    cv.b = __float2bfloat16(x);    // HW RNE convert
    return cv.u;
}

// ===========================================================================
// Fragment-tiled operand layouts (each MFMA B-fragment = one contiguous
// coalesced 1KB wave load):
//   emb5: tile ((b*128 + jc)*16 + (w*4 + nt)), elem = lane*8 + e
//         maps (b, j = jc*32 + (lane>>4)*8 + e, d = w*64 + nt*16 + (lane&15))
//   w5:   tile ((w*4 + et)*8 + kt), elem = lane*8 + ee
//         maps (e = w*64 + et*16 + (lane&15), d = kt*32 + (lane>>4)*8 + ee)
// ===========================================================================

// ---------------------------------------------------------------------------
// K1: embedding in emb5 layout (LDS-staged scatter -> coalesced stream-out),
// W -> w5 (blk < 256), and per-fused-block band-start jcmin (wave 0: two
// 64-ary ballot searches per block, hidden under the sincos work).
// ---------------------------------------------------------------------------
__global__ __launch_bounds__(256) void embt_kernel(const float* __restrict__ t,
                                                   const float* __restrict__ W,
                                                   unsigned short* __restrict__ emb5,
                                                   unsigned short* __restrict__ w5,
                                                   int* __restrict__ jcmin_out) {
    int blk = blockIdx.x;
    int tid = threadIdx.x;

    if (blk < 256) {               // W[e][d] -> w5 fragment tiles (scattered 2B)
        int e = blk, dd = tid;
        int wv = e >> 6, et = (e >> 4) & 3, l15 = e & 15;
        int kt = dd >> 5, kgg = (dd >> 3) & 3, ee = dd & 7;
        w5[(size_t)(((wv * 4 + et) * 8 + kt) * 512) + (kgg * 16 + l15) * 8 + ee]
            = f2bf(W[e * D + dd]);
    }

    // wave 0: band-start searches for fused blocks 2*blk, 2*blk+1
    if (tid < 64) {
#pragma unroll
        for (int s = 0; s < 2; ++s) {
            int fb = blk * 2 + s;
            int b2 = fb >> 8;
            int i0 = (fb & 255) * RPB;
            const float* tb2 = t + b2 * S;
            float tcut = tb2[i0] - DT_CUT;
            int lo = 0, hi = i0;                 // invariant: t[hi] >= tcut
            while (hi > lo) {
                int step = ((hi - lo) + 63) >> 6;
                int p = min(lo + tid * step, hi);
                unsigned long long mb = __ballot(tb2[p] < tcut);
                int cnt = __popcll(mb);
                int nlo = (cnt == 0) ? lo : (lo + (cnt - 1) * step + 1);
                int nhi = (cnt == 0) ? nlo : min(lo + cnt * step, hi);
                lo = nlo; hi = nhi;
            }
            if (tid == 0) jcmin_out[fb] = lo >> 5;
        }
    }

    __shared__ unsigned short tile[8192];       // 16 KiB, final global order
    int j_local = tid & 31;
    int fg      = tid >> 5;                     // 8 groups x 16 freqs
    int b       = blk >> 7;
    int jc      = blk & 127;
    float tv = t[b * S + jc * 32 + j_local];
    int kg = j_local >> 3, e = j_local & 7;
    const float c2 = -0.1038102552f;            // -2*log2(10000)/256
#pragma unroll
    for (int kk = 0; kk < 16; ++kk) {
        int k = fg * 16 + kk;
        float te = tv * exp2f(c2 * (float)(k + 1));
        float sn, cs;
        __sincosf(te, &sn, &cs);
        int base = (k >> 3) * 512 + kg * 128 + e;      // (d>>4)*512 + (kg*16+ln)*8 + e
        int ln0 = 2 * (k & 7);
        tile[base + ln0 * 8]       = f2bf(sn);         // d even -> sin
        tile[base + (ln0 + 1) * 8] = f2bf(cs);         // d odd  -> cos
    }
    __syncthreads();
    const uint4* src = (const uint4*)tile;             // 1024 x 16B
    uint4* dst = (uint4*)(emb5 + (size_t)blk * 8192);
#pragma unroll
    for (int p = 0; p < 4; ++p) dst[p * 256 + tid] = src[p * 256 + tid];
}

// ---------------------------------------------------------------------------
// K2: fused band-GEMM + LayerNorm + decoder-GEMM + softplus.
// Block = 16 rows x 256 d/e, 4 waves. Band loop 2-deep pipelined; decoder
// weights hoisted across the LN barriers; XCD-swizzled block ids.
// ---------------------------------------------------------------------------
__global__ __launch_bounds__(256, 4) void fused_kernel(
    const float* __restrict__ t, const unsigned short* __restrict__ emb5,
    const unsigned short* __restrict__ w5, const int* __restrict__ jcmin_arr,
    const float* __restrict__ gamma, const float* __restrict__ beta,
    const float* __restrict__ w_t, const float* __restrict__ b_t,
    float* __restrict__ out) {
    int bid  = blockIdx.x;
    int blk  = (bid & 7) * (NBLK / 8) + (bid >> 3);   // XCD swizzle (bijective)
    int b    = blk >> 8;                 // 256 blocks per batch
    int i0   = (blk & 255) * RPB;
    int tid  = threadIdx.x;
    int w    = tid >> 6;
    int lane = tid & 63;
    int ln15 = lane & 15;
    int kg   = lane >> 4;
    const float* tb = t + b * S;

    float ti = tb[i0 + ln15];            // A row = ln15
    int irow = i0 + ln15;
    int jcmin = jcmin_arr[blk];
    int jcmax = (i0 + RPB - 1) >> 5;

    // ---- band GEMM: C[m, d] += scores[m, k] * emb[k, d], 2-deep pipelined
    f32x4 acc[4];
#pragma unroll
    for (int nt = 0; nt < 4; ++nt) acc[nt] = (f32x4){0.f, 0.f, 0.f, 0.f};

    const unsigned short* ebase =
        emb5 + ((size_t)(b * 128) * 16 + w * 4) * 512 + lane * 8;
    short8 c0, c1, c2, c3;
    float4 ta, tb4;
    {
        const unsigned short* p = ebase + (size_t)jcmin * 8192;
        c0 = *(const short8*)(p);
        c1 = *(const short8*)(p + 512);
        c2 = *(const short8*)(p + 1024);
        c3 = *(const short8*)(p + 1536);
        ta  = *(const float4*)&tb[jcmin * 32 + kg * 8];
        tb4 = *(const float4*)&tb[jcmin * 32 + kg * 8 + 4];
    }
    for (int jc = jcmin; jc <= jcmax; ++jc) {
        int j0 = jc * 32;
        short8 n0, n1, n2, n3;
        float4 nta, ntb;
        if (jc < jcmax) {                // prefetch next chunk
            const unsigned short* p = ebase + (size_t)(jc + 1) * 8192;
            n0 = *(const short8*)(p);
            n1 = *(const short8*)(p + 512);
            n2 = *(const short8*)(p + 1024);
            n3 = *(const short8*)(p + 1536);
            nta = *(const float4*)&tb[j0 + 32 + kg * 8];
            ntb = *(const float4*)&tb[j0 + 32 + kg * 8 + 4];
        }
        // scores (A fragment) while prefetch is in flight
        float tj[8] = {ta.x, ta.y, ta.z, ta.w, tb4.x, tb4.y, tb4.z, tb4.w};
        union { short8 v; unsigned short u[8]; } a;
        if (j0 + 31 <= i0) {              // fully causal chunk
#pragma unroll
            for (int e = 0; e < 8; ++e) {
                float dt = ti - tj[e];
                a.u[e] = f2bf(__expf(-0.5f * dt * dt));
            }
        } else {                          // diagonal chunk: mask j > i
#pragma unroll
            for (int e = 0; e < 8; ++e) {
                float dt = ti - tj[e];
                float sc = __expf(-0.5f * dt * dt);
                a.u[e] = (j0 + kg * 8 + e <= irow) ? f2bf(sc) : (unsigned short)0;
            }
        }
        acc[0] = __builtin_amdgcn_mfma_f32_16x16x32_bf16(a.v, c0, acc[0], 0, 0, 0);
        acc[1] = __builtin_amdgcn_mfma_f32_16x16x32_bf16(a.v, c1, acc[1], 0, 0, 0);
        acc[2] = __builtin_amdgcn_mfma_f32_16x16x32_bf16(a.v, c2, acc[2], 0, 0, 0);
        acc[3] = __builtin_amdgcn_mfma_f32_16x16x32_bf16(a.v, c3, acc[3], 0, 0, 0);
        c0 = n0; c1 = n1; c2 = n2; c3 = n3;
        ta = nta; tb4 = ntb;
    }

    // ---- hoist decoder kt=0 weight frags (independent of H / LN barriers)
    const unsigned short* wbase = w5 + (size_t)(w * 4 * 8) * 512 + lane * 8;
    short8 w0 = *(const short8*)(wbase + (size_t)(0 * 8) * 512);
    short8 w1 = *(const short8*)(wbase + (size_t)(1 * 8) * 512);
    short8 w2 = *(const short8*)(wbase + (size_t)(2 * 8) * 512);
    short8 w3 = *(const short8*)(wbase + (size_t)(3 * 8) * 512);

    // ---- LayerNorm (row m = kg*4 + reg; col d = w*64 + nt*16 + ln15)
    __shared__ float2 s_ln[4][RPB];
    __shared__ unsigned short H[RPB][264];       // +8 pad: conflict-free b128
    __shared__ float s_dec[4][RPB];

#pragma unroll
    for (int reg = 0; reg < 4; ++reg) {
        float s = acc[0][reg] + acc[1][reg] + acc[2][reg] + acc[3][reg];
        float q = acc[0][reg] * acc[0][reg] + acc[1][reg] * acc[1][reg]
                + acc[2][reg] * acc[2][reg] + acc[3][reg] * acc[3][reg];
#pragma unroll
        for (int m = 1; m < 16; m <<= 1) {
            s += __shfl_xor(s, m);
            q += __shfl_xor(q, m);
        }
        if (ln15 == 0) s_ln[w][kg * 4 + reg] = make_float2(s, q);
    }
    __syncthreads();

    float g[4], be[4];
#pragma unroll
    for (int nt = 0; nt < 4; ++nt) {
        g[nt]  = gamma[w * 64 + nt * 16 + ln15];
        be[nt] = beta[w * 64 + nt * 16 + ln15];
    }
#pragma unroll
    for (int reg = 0; reg < 4; ++reg) {
        int r = kg * 4 + reg;
        float2 p0 = s_ln[0][r], p1 = s_ln[1][r], p2 = s_ln[2][r], p3 = s_ln[3][r];
        float sum = p0.x + p1.x + p2.x + p3.x;
        float sq  = p0.y + p1.y + p2.y + p3.y;
        float mu  = sum * (1.0f / D);
        float var = fmaxf(sq * (1.0f / D) - mu * mu, 0.0f);
        float rstd = rsqrtf(var + 1e-6f);
#pragma unroll
        for (int nt = 0; nt < 4; ++nt) {
            float h = (acc[nt][reg] - mu) * rstd * g[nt] + be[nt];
            H[r][w * 64 + nt * 16 + ln15] = f2bf(h);
        }
    }
    __syncthreads();

    // ---- decoder GEMM: C2[m, e] = sum_d H[m, d] * W[e, d], kt pipelined
    f32x4 acc2[4];
#pragma unroll
    for (int et = 0; et < 4; ++et) acc2[et] = (f32x4){0.f, 0.f, 0.f, 0.f};

    short8 afr[8];
#pragma unroll
    for (int kt = 0; kt < 8; ++kt)
        afr[kt] = *(const short8*)&H[ln15][kt * 32 + kg * 8];

#pragma unroll
    for (int kt = 0; kt < 8; ++kt) {
        short8 nw0, nw1, nw2, nw3;
        if (kt < 7) {
            const unsigned short* p = wbase + (size_t)(kt + 1) * 512;
            nw0 = *(const short8*)(p + (size_t)(0 * 8) * 512);
            nw1 = *(const short8*)(p + (size_t)(1 * 8) * 512);
            nw2 = *(const short8*)(p + (size_t)(2 * 8) * 512);
            nw3 = *(const short8*)(p + (size_t)(3 * 8) * 512);
        }
        acc2[0] = __builtin_amdgcn_mfma_f32_16x16x32_bf16(afr[kt], w0, acc2[0], 0, 0, 0);
        acc2[1] = __builtin_amdgcn_mfma_f32_16x16x32_bf16(afr[kt], w1, acc2[1], 0, 0, 0);
        acc2[2] = __builtin_amdgcn_mfma_f32_16x16x32_bf16(afr[kt], w2, acc2[2], 0, 0, 0);
        acc2[3] = __builtin_amdgcn_mfma_f32_16x16x32_bf16(afr[kt], w3, acc2[3], 0, 0, 0);
        w0 = nw0; w1 = nw1; w2 = nw2; w3 = nw3;
    }

    // ---- epilogue: relu -> *w_t -> reduce over e -> softplus
    float wt[4];
#pragma unroll
    for (int et = 0; et < 4; ++et) wt[et] = w_t[w * 64 + et * 16 + ln15];
#pragma unroll
    for (int reg = 0; reg < 4; ++reg) {
        float v = 0.f;
#pragma unroll
        for (int et = 0; et < 4; ++et)
            v = fmaf(fmaxf(acc2[et][reg], 0.f), wt[et], v);
#pragma unroll
        for (int m = 1; m < 16; m <<= 1) v += __shfl_xor(v, m);
        if (ln15 == 0) s_dec[w][kg * 4 + reg] = v;
    }
    __syncthreads();
    if (tid < RPB) {
        float tot = s_dec[0][tid] + s_dec[1][tid] + s_dec[2][tid] + s_dec[3][tid] + b_t[0];
        float o = fmaxf(tot, 0.0f) + log1pf(expf(-fabsf(tot)));   // softplus
        out[(size_t)blk * RPB + tid] = o;
    }
}

// ---------------------------------------------------------------------------
extern "C" void kernel_launch(void* const* d_in, const int* in_sizes, int n_in,
                              void* d_out, int out_size, void* d_ws, size_t ws_size,
                              hipStream_t stream) {
    // inputs: 0 event_type(i32) 1 event_time(f32) 2 arrival_times(f32)
    //         3 W_in 4 w_t 5 b_t 6 ln_gamma 7 ln_beta
    const float* t   = (const float*)d_in[1];
    const float* W   = (const float*)d_in[3];
    const float* wt  = (const float*)d_in[4];
    const float* bt  = (const float*)d_in[5];
    const float* gam = (const float*)d_in[6];
    const float* bet = (const float*)d_in[7];
    float* out = (float*)d_out;

    char* ws = (char*)d_ws;
    unsigned short* emb5  = (unsigned short*)ws;                       // 8 MiB
    unsigned short* w5    = (unsigned short*)(ws + (size_t)8388608);   // 128 KiB
    int*            jcmin = (int*)(ws + (size_t)8519680);              // 4 KiB

    embt_kernel<<<dim3(512), dim3(256), 0, stream>>>(t, W, emb5, w5, jcmin);
    fused_kernel<<<dim3(NBLK), dim3(256), 0, stream>>>(
        t, emb5, w5, jcmin, gam, bet, wt, bt, out);
}